// Round 10
// baseline (119.913 us; speedup 1.0000x reference)
//
#include <hip/hip_runtime.h>
#include <math.h>

#define DEVI __device__ __forceinline__

constexpr int B = 2, P = 16, G = 128, E = 96, N = 128, CO = 2;

DEVI float lrelu(float x) { return x > 0.f ? x : 0.01f * x; }

// ---- workspace layout (floats) ----
constexpr int OFF_U1     = 0;                       // 524288
constexpr int OFF_V1     = OFF_U1 + 524288;         // 3145728
constexpr int OFF_MAXPU0 = OFF_V1 + 3145728;        // 32768
constexpr int OFF_MAXEV0 = OFF_MAXPU0 + 32768;      // 32768
constexpr int OFF_MP110  = OFF_MAXEV0 + 32768;      // 32768 (== me011)
constexpr int OFF_MG110  = OFF_MP110 + 32768;       // 4096
constexpr int OFF_S001A  = OFF_MG110 + 4096;        // 24576 (== mg011)
constexpr int OFF_RMP    = OFF_S001A + 24576;       // 1024
constexpr int OFF_RMG    = OFF_RMP + 1024;          // 128
constexpr int OFF_RME    = OFF_RMG + 128;           // 512
constexpr int OFF_RMG011 = OFF_RME + 512;           // 384
constexpr int OFF_WT     = OFF_RMG011 + 384;        // 5*16384
constexpr int OFF_PART   = OFF_WT + 81920;          // 256*1664
// part[b][nc][gc][1664]: [0:128)=pm110(nn*16+p), [128:896)=psum(nn*96+e), [896:1664)=pmax

// ---------------------------------------------------------------------------
// K1: fused layer 0, one block per (b,n). V0 in two 64-g halves (LDS ~68KB ->
// 2 blocks/CU). + W1 transpose tail.
__global__ void __launch_bounds__(256) k_layer0(
    const float* __restrict__ x110, const float* __restrict__ x011,
    const float* __restrict__ x001,
    const float* __restrict__ W0_110, const float* __restrict__ b0_110,
    const float* __restrict__ W0_011, const float* __restrict__ b0_011,
    const float* __restrict__ W0_001, const float* __restrict__ b0_001,
    const float* __restrict__ W1,
    float* __restrict__ maxpU0g, float* __restrict__ maxeV0g,
    float* __restrict__ mp110, float* __restrict__ mg110,
    float* __restrict__ s001a,
    float* __restrict__ rmpG, float* __restrict__ rmgG,
    float* __restrict__ rmeG, float* __restrict__ rmg011G,
    float* __restrict__ wT) {
  __shared__ float xs[4 * 16 * 128];       // 32KB
  __shared__ float v0h[64 * 97];           // 24.25KB (one g-half of V0)
  __shared__ float u0[16 * 128];           // 8KB
  __shared__ float rmp[512], rmgS[64], rme[256], rmg011L[192];
  __shared__ float mpu[128], mev[128], part[256];
  const int bn = blockIdx.x, b = bn >> 7, n = bn & 127, tid = threadIdx.x;

  {  // stage x110[b]
    const float4* xsrc = (const float4*)(x110 + (size_t)b * 8192);
    float4* xdst = (float4*)xs;
#pragma unroll
    for (int k = 0; k < 8; k++) xdst[tid + k * 256] = xsrc[tid + k * 256];
  }
  {  // rme[c][g] = max_e x011 (row-f4 reads, L2-hot)
    int c = tid >> 7, g = tid & 127;
    const float4* r = (const float4*)(x011 + ((size_t)(b * 2 + c) * 128 + g) * 96);
    float m = -INFINITY;
#pragma unroll
    for (int j = 0; j < 24; j++) {
      float4 v = r[j];
      m = fmaxf(m, fmaxf(fmaxf(v.x, v.y), fmaxf(v.z, v.w)));
    }
    rme[tid] = m;
  }
  __syncthreads();
  for (int i = tid; i < 512; i += 256) {   // rmp[c][g] = max_p x110
    int c = i >> 7, g = i & 127;
    float m = -INFINITY;
    for (int p = 0; p < P; p++) m = fmaxf(m, xs[(c * 16 + p) * 128 + g]);
    rmp[i] = m;
  }
  if (tid < 64) {                          // rmgS[c][p] = max_g x110
    int c = tid >> 4, p = tid & 15;
    float m = -INFINITY;
    for (int g = 0; g < G; g++) m = fmaxf(m, xs[(c * 16 + p) * 128 + g]);
    rmgS[tid] = m;
  }
  if (tid < 192) {                         // rmg011L[c][e] = max_g x011
    int c = tid / 96, e = tid % 96;
    const float* pp = x011 + ((size_t)(b * 2 + c) * 128) * 96 + e;
    float m = -INFINITY;
    for (int g = 0; g < G; g++) m = fmaxf(m, pp[g * 96]);
    rmg011L[tid] = m;
  }
  __syncthreads();
  float w0[4], w1[4], w2[4];
#pragma unroll
  for (int cc = 0; cc < 4; cc++) {
    w0[cc] = W0_110[n * 4 + cc];
    w1[cc] = W0_110[512 + n * 4 + cc];
    w2[cc] = W0_110[1024 + n * 4 + cc];
  }
  float we0 = W0_011[512 + n * 2], we1 = W0_011[512 + n * 2 + 1];
  float bu = b0_110[n] + b0_110[128 + n] + b0_110[256 + n] + b0_011[256 + n];
  float vw00 = W0_011[n * 2], vw01 = W0_011[n * 2 + 1];
  float vw10 = W0_011[256 + n * 2], vw11 = W0_011[256 + n * 2 + 1];
  float w001 = W0_001[n];
  float bv = b0_011[n] + b0_011[128 + n] + b0_001[n];

#pragma unroll
  for (int k = 0; k < 8; k++) {            // U0 row
    int i = tid + k * 256, p = i >> 7, g = i & 127;
    float acc = bu + we0 * rme[g] + we1 * rme[128 + g];
#pragma unroll
    for (int cc = 0; cc < 4; cc++)
      acc += w0[cc] * xs[(cc * 16 + p) * 128 + g] + w1[cc] * rmp[cc * 128 + g]
           + w2[cc] * rmgS[cc * 16 + p];
    u0[i] = acc;
  }
  __syncthreads();
  if (tid < 128) {                         // mpu[g] = max_p U0
    float m = -INFINITY;
    for (int p = 0; p < P; p++) m = fmaxf(m, u0[p * 128 + tid]);
    mpu[tid] = m;
    maxpU0g[bn * 128 + tid] = m;
  }
  __syncthreads();

  const float* xa = x011 + (size_t)(b * 2) * 12288;
  const float* xb = xa + 12288;
  const float* xc = x001 + b * 96;
  float runMax = -INFINITY;                // s001a register accumulator (tid<96)

  for (int h2 = 0; h2 < 2; h2++) {
    // V0 half: g' in [0,64), global g = h2*64+g'
    for (int k = 0; k < 24; k++) {
      int i = tid + k * 256;
      int gp = i / 96, e = i - gp * 96;
      int g = h2 * 64 + gp;
      float val = bv + vw00 * xa[g * 96 + e] + vw01 * xb[g * 96 + e]
                + vw10 * rmg011L[e] + vw11 * rmg011L[96 + e] + w001 * xc[e];
      v0h[gp * 97 + e] = val;
    }
    __syncthreads();
    {                                      // maxeV partials: 64 g' x 4 q
      int gp = tid & 63, q = tid >> 6;
      const float* r = &v0h[gp * 97 + q * 24];
      float m = -INFINITY;
      for (int j = 0; j < 24; j++) m = fmaxf(m, r[j]);
      part[q * 64 + gp] = m;
    }
    __syncthreads();
    if (tid < 64) {
      float m = fmaxf(fmaxf(part[tid], part[64 + tid]),
                      fmaxf(part[128 + tid], part[192 + tid]));
      int g = h2 * 64 + tid;
      mev[g] = m;
      maxeV0g[bn * 128 + g] = m;
      mp110[bn * 128 + g] = lrelu(mpu[g] + m);   // == me011
    }
    if (tid < 96) {                        // s001a running max over g
      for (int gp = 0; gp < 64; gp++)
        runMax = fmaxf(runMax, mpu[h2 * 64 + gp] + v0h[gp * 97 + tid]);
    }
    __syncthreads();
  }
  {                                        // mg110 partials over g-chunks
    int p = tid >> 4, ch = tid & 15;
    float m = -INFINITY;
    for (int g = ch * 8; g < ch * 8 + 8; g++)
      m = fmaxf(m, u0[p * 128 + g] + mev[g]);
    part[tid] = m;
  }
  if (tid < 96) s001a[bn * 96 + tid] = lrelu(runMax);
  __syncthreads();
  if (tid < 16) {
    float m = -INFINITY;
    for (int ch = 0; ch < 16; ch++) m = fmaxf(m, part[tid * 16 + ch]);
    mg110[bn * 16 + tid] = lrelu(m);
  }
  if (n == 0) {
    for (int i = tid; i < 512; i += 256) rmpG[b * 512 + i] = rmp[i];
    if (tid < 64) rmgG[b * 64 + tid] = rmgS[tid];
    rmeG[b * 256 + tid] = rme[tid];
    if (tid < 192) rmg011G[b * 192 + tid] = rmg011L[tid];
  }
  // ---- W1 transpose/fold tail: wT[m][c][n] ----
  {
    const int gt = bn * 256 + tid;
#pragma unroll
    for (int it = 0; it < 2; it++) {
      int idx = gt + it * 65536;
      if (idx < 81920) {
        int m = idx >> 14, r = idx & 16383;
        int c = r >> 7, nn = r & 127;
        float v;
        if (m == 0)      v = W1[nn * 128 + c];
        else if (m == 1) v = W1[16384 + nn * 128 + c] + W1[5 * 16384 + nn * 128 + c];
        else if (m == 2) v = W1[2 * 16384 + nn * 128 + c];
        else if (m == 3) v = W1[3 * 16384 + nn * 128 + c];
        else             v = W1[4 * 16384 + nn * 128 + c] + W1[6 * 16384 + nn * 128 + c];
        wT[idx] = v;
      }
    }
  }
}

// ---------------------------------------------------------------------------
// K2: layer 1 PURE GEMMs. One block per (b,g), 512 threads.
// V1: threads 0-255, 4n x 12e tiles. U1: threads 256-511, 8p each.
__global__ void __launch_bounds__(512) k_layer1c(
    const float* __restrict__ x110, const float* __restrict__ x011,
    const float* __restrict__ x001,
    const float* __restrict__ W0_110, const float* __restrict__ b0_110,
    const float* __restrict__ W0_011, const float* __restrict__ b0_011,
    const float* __restrict__ W0_001, const float* __restrict__ b0_001,
    const float* __restrict__ maxpU0g, const float* __restrict__ maxeV0g,
    const float* __restrict__ rmpG, const float* __restrict__ rmgG,
    const float* __restrict__ rmeG, const float* __restrict__ rmg011G,
    const float* __restrict__ wT,
    float* __restrict__ U1, float* __restrict__ V1) {
  __shared__ float s110c[128 * 16];
  __shared__ float s011c[128 * 96];
  __shared__ float W0L110[1536], W0L011[768], W0L001[128];
  __shared__ float busum[128], bvsum[128], mpu[128], mev[128];
  __shared__ float x011row[192], rmg011s[192], x001s[96];
  __shared__ float x110col[64], rmg110p[64], rmp4[4], rme2[2];
  const int blk = blockIdx.x;
  const int b = blk >> 7, g = blk & 127;
  const int tid = threadIdx.x;

  for (int i = tid; i < 1536; i += 512) W0L110[i] = W0_110[i];
  for (int i = tid; i < 768; i += 512) W0L011[i] = W0_011[i];
  if (tid < 128) {
    W0L001[tid] = W0_001[tid];
    busum[tid] = b0_110[tid] + b0_110[128 + tid] + b0_110[256 + tid]
               + b0_011[256 + tid];
    bvsum[tid] = b0_011[tid] + b0_011[128 + tid] + b0_001[tid];
    mpu[tid] = maxpU0g[(b * 128 + tid) * 128 + g];
    mev[tid] = maxeV0g[(b * 128 + tid) * 128 + g];
  } else if (tid >= 256 && tid < 448) {
    int i = tid - 256;
    int c = i / 96, e = i % 96;
    x011row[i] = x011[((size_t)(b * 2 + c) * 128 + g) * 96 + e];
    rmg011s[i] = rmg011G[b * 192 + i];
  } else if (tid >= 448 && tid < 512) {
    int i = tid - 448;
    int c = i >> 4, p = i & 15;
    x110col[i] = x110[((size_t)(b * 4 + c) * 16 + p) * 128 + g];
    rmg110p[i] = rmgG[b * 64 + i];
  } else if (tid >= 128 && tid < 224) {
    x001s[tid - 128] = x001[b * 96 + tid - 128];
  } else if (tid >= 224 && tid < 228) {
    rmp4[tid - 224] = rmpG[(b * 4 + tid - 224) * 128 + g];
  } else if (tid >= 228 && tid < 230) {
    rme2[tid - 228] = rmeG[(b * 2 + tid - 228) * 128 + g];
  }
  __syncthreads();

#pragma unroll
  for (int k = 0; k < 4; k++) {            // s110 column (c,p)
    int i = tid + k * 512, c = i >> 4, p = i & 15;
    float acc = busum[c] + W0L011[512 + c * 2] * rme2[0]
              + W0L011[512 + c * 2 + 1] * rme2[1];
#pragma unroll
    for (int cc = 0; cc < 4; cc++)
      acc += W0L110[c * 4 + cc] * x110col[cc * 16 + p]
           + W0L110[512 + c * 4 + cc] * rmp4[cc]
           + W0L110[1024 + c * 4 + cc] * rmg110p[cc * 16 + p];
    s110c[i] = lrelu(acc + mev[c]);
  }
  for (int k = 0; k < 24; k++) {           // s011 column (c,e)
    int i = tid + k * 512;
    int c = i / 96, e = i - c * 96;
    float v = bvsum[c]
            + W0L011[c * 2] * x011row[e] + W0L011[c * 2 + 1] * x011row[96 + e]
            + W0L011[256 + c * 2] * rmg011s[e]
            + W0L011[256 + c * 2 + 1] * rmg011s[96 + e]
            + W0L001[c] * x001s[e];
    s011c[i] = lrelu(v + mpu[c]);
  }
  __syncthreads();

  const float* w0T = wT;
  const float* w3T = wT + 3 * 16384;

  if (tid < 256) {
    // ---- V1: 4n x 12e per thread ----
    int n0 = (tid >> 3) * 4, e0 = (tid & 7) * 12;
    float4 acc[4][3];
#pragma unroll
    for (int ni = 0; ni < 4; ni++)
#pragma unroll
      for (int k = 0; k < 3; k++) acc[ni][k] = make_float4(0.f, 0.f, 0.f, 0.f);
    for (int c = 0; c < 128; c++) {
      float4 wv = *(const float4*)&w3T[c * 128 + n0];
      float4 s0 = *(const float4*)&s011c[c * 96 + e0];
      float4 s1 = *(const float4*)&s011c[c * 96 + e0 + 4];
      float4 s2 = *(const float4*)&s011c[c * 96 + e0 + 8];
#pragma unroll
      for (int ni = 0; ni < 4; ni++) {
        float wc = ni == 0 ? wv.x : ni == 1 ? wv.y : ni == 2 ? wv.z : wv.w;
        acc[ni][0].x += wc * s0.x; acc[ni][0].y += wc * s0.y;
        acc[ni][0].z += wc * s0.z; acc[ni][0].w += wc * s0.w;
        acc[ni][1].x += wc * s1.x; acc[ni][1].y += wc * s1.y;
        acc[ni][1].z += wc * s1.z; acc[ni][1].w += wc * s1.w;
        acc[ni][2].x += wc * s2.x; acc[ni][2].y += wc * s2.y;
        acc[ni][2].z += wc * s2.z; acc[ni][2].w += wc * s2.w;
      }
    }
#pragma unroll
    for (int ni = 0; ni < 4; ni++) {
      float* dst = V1 + ((size_t)((b * 128 + g) * 128 + n0 + ni)) * 96 + e0;
#pragma unroll
      for (int k = 0; k < 3; k++) *(float4*)(dst + k * 4) = acc[ni][k];
    }
  } else {
    // ---- U1: n lane-contiguous, 8 p per thread ----
    int t = tid - 256;
    int n = t & 127, ph = t >> 7;
    float a[8];
#pragma unroll
    for (int j = 0; j < 8; j++) a[j] = 0.f;
    for (int c = 0; c < 128; c++) {
      float w0v = w0T[c * 128 + n];
      float4 s0 = *(const float4*)&s110c[c * 16 + ph * 8];
      float4 s1 = *(const float4*)&s110c[c * 16 + ph * 8 + 4];
      a[0] += w0v * s0.x; a[1] += w0v * s0.y; a[2] += w0v * s0.z; a[3] += w0v * s0.w;
      a[4] += w0v * s1.x; a[5] += w0v * s1.y; a[6] += w0v * s1.z; a[7] += w0v * s1.w;
    }
    float* dst = U1 + ((size_t)((b * 128 + g) * 16 + ph * 8)) * 128 + n;
#pragma unroll
    for (int j = 0; j < 8; j++) dst[j * 128] = a[j];
  }
}

// ---------------------------------------------------------------------------
// K3: partial g-reduction. grid = (b, nc of 8n, gc of 16g) = 256 blocks.
__global__ void __launch_bounds__(256) k_post3(
    const float* __restrict__ U1, const float* __restrict__ V1,
    const float* __restrict__ s001a, const float* __restrict__ mp110,
    const float* __restrict__ mg110,
    const float* __restrict__ wT, const float* __restrict__ b1,
    float* __restrict__ partOut) {
  constexpr int GS = 16;
  __shared__ float Vt[GS][8][104];         // 53.2KB (pitch 104 keeps f4 align)
  __shared__ float Ut[GS][16][9];          // 9.2KB
  __shared__ float bfL[8][GS];
  __shared__ float egL[8][96];
  __shared__ float cpL[8][16];
  __shared__ float partE[GS][8][4];
  __shared__ float mxeV[GS][8], mxpU[GS][8];
  __shared__ float bbL[8], bvL[8];
  const int blk = blockIdx.x;
  const int b = blk >> 7, nc = (blk >> 3) & 15, gc = blk & 7;
  const int n0 = nc * 8, g0 = gc * 16;
  const int tid = threadIdx.x;
  const float* w15T = wT + 16384;
  const float* w2T  = wT + 2 * 16384;
  const float* w46T = wT + 4 * 16384;

  if (tid < 8) {
    int n = n0 + tid;
    bbL[tid] = b1[n] + b1[128 + n] + b1[256 + n] + b1[640 + n];
    bvL[tid] = b1[384 + n] + b1[512 + n] + b1[768 + n];
  }
  if (tid < 128) {   // bf[nn][gl]
    int nn = tid >> 4, gl = tid & 15;
    float acc = 0.f;
    for (int c = 0; c < 128; c++)
      acc += w15T[c * 128 + n0 + nn] * mp110[(b * 128 + c) * 128 + g0 + gl];
    bfL[nn][gl] = acc;
  } else {           // cp[nn][p]
    int i = tid - 128;
    int nn = i >> 4, p = i & 15;
    float acc = 0.f;
    for (int c = 0; c < 128; c++)
      acc += w2T[c * 128 + n0 + nn] * mg110[(b * 128 + c) * 16 + p];
    cpL[nn][p] = acc;
  }
#pragma unroll
  for (int k = 0; k < 3; k++) {   // eg[nn][e]
    int s = tid + k * 256;
    int nn = s / 96, e = s % 96;
    float acc = 0.f;
    for (int c = 0; c < 128; c++)
      acc += w46T[c * 128 + n0 + nn] * s001a[b * 12288 + c * 96 + e];
    egL[nn][e] = acc;
  }
  __syncthreads();

  const size_t Ubase = (size_t)b * 128 * 16 * 128;
  const size_t Vbase = (size_t)b * 128 * 128 * 96;
#pragma unroll
  for (int k = 0; k < 12; k++) {   // stage V (+bv+eg), float4
    int i4 = tid + k * 256;        // 3072 f4
    int gs = i4 / 192, r = i4 % 192, nn = r / 24, e4 = r % 24;
    float4 v = *(const float4*)(V1 + Vbase
                 + ((size_t)(g0 + gs) * 128 + n0 + nn) * 96 + e4 * 4);
    float bvv = bvL[nn];
    const float* eg = &egL[nn][e4 * 4];
    float4 o = make_float4(v.x + bvv + eg[0], v.y + bvv + eg[1],
                           v.z + bvv + eg[2], v.w + bvv + eg[3]);
    *(float4*)&Vt[gs][nn][e4 * 4] = o;
  }
#pragma unroll
  for (int k = 0; k < 8; k++) {    // stage U (+bb+cp+bf)
    int i = tid + k * 256;
    int gs = i >> 7, r = i & 127, p = r >> 3, nn = r & 7;
    float u = U1[Ubase + ((size_t)(g0 + gs) * 16 + p) * 128 + n0 + nn];
    Ut[gs][p][nn] = u + bbL[nn] + cpL[nn][p] + bfL[nn][gs];
  }
  __syncthreads();
#pragma unroll
  for (int k = 0; k < 2; k++) {    // partial max_e
    int i = tid + k * 256;
    int gs = i >> 5, nn = (i >> 2) & 7, ec = i & 3;
    float m = -INFINITY;
    for (int e = ec * 24; e < ec * 24 + 24; e++) m = fmaxf(m, Vt[gs][nn][e]);
    partE[gs][nn][ec] = m;
  }
  __syncthreads();
  if (tid < 128) {
    int gs = tid >> 3, nn = tid & 7;
    mxeV[gs][nn] = fmaxf(fmaxf(partE[gs][nn][0], partE[gs][nn][1]),
                         fmaxf(partE[gs][nn][2], partE[gs][nn][3]));
    float m = -INFINITY;
    for (int p = 0; p < 16; p++) m = fmaxf(m, Ut[gs][p][nn]);
    mxpU[gs][nn] = m;
  }
  __syncthreads();

  float* pb = partOut + (size_t)blk * 1664;
  if (tid < 128) {
    int nn = tid >> 4, p = tid & 15;
    float a = 0.f;
#pragma unroll
    for (int gs = 0; gs < GS; gs++)
      a += lrelu(Ut[gs][p][nn] + mxeV[gs][nn]);
    pb[tid] = a;
  }
#pragma unroll
  for (int k = 0; k < 3; k++) {
    int s = tid + k * 256;
    int nn = s / 96, e = s % 96;
    float a = 0.f, m = -INFINITY;
#pragma unroll
    for (int gs = 0; gs < GS; gs++) {
      float pre = mxpU[gs][nn] + Vt[gs][nn][e];
      a += lrelu(pre);
      m = fmaxf(m, pre);
    }
    pb[128 + s] = a;
    pb[896 + s] = m;
  }
}

// ---------------------------------------------------------------------------
// K4: heads + partial-fold (absorbs old k_combine). One block per (b,o), 256 thr.
__global__ void __launch_bounds__(256) k_final(
    const float* __restrict__ partIn,
    const float* __restrict__ Wact, const float* __restrict__ bact,
    const float* __restrict__ Wcrit, const float* __restrict__ bcrit,
    float* __restrict__ out) {
  __shared__ float buf[128][97];           // m011e then s001b
  __shared__ float m110s[128][17];
  __shared__ float sm011[N], sm001[N], sce1[E], sce[E], scp[P], srow[P], scol[E];
  const int bo = blockIdx.x;
  const int o = bo & 1, b = bo >> 1;
  const int t = threadIdx.x;
  const float* pbB = partIn + (size_t)(b * 16) * 8 * 1664;

  // fold m110 partials: 2048 items over 8 gc
#pragma unroll
  for (int k = 0; k < 8; k++) {
    int i = t + k * 256;                   // i = nc*128 + (nn*16+p)
    int nc = i >> 7, j = i & 127;
    const float* base = pbB + (size_t)(nc * 8) * 1664;
    float a = 0.f;
#pragma unroll
    for (int gc = 0; gc < 8; gc++) a += base[gc * 1664 + j];
    m110s[nc * 8 + (j >> 4)][j & 15] = a * (1.f / G);
  }
  // fold m011e partials into buf
#pragma unroll
  for (int k = 0; k < 48; k++) {
    int i = t + k * 256;                   // i = nc*768 + (nn*96+e)
    int nc = i / 768, r = i % 768;
    const float* base = pbB + (size_t)(nc * 8) * 1664;
    float a = 0.f;
#pragma unroll
    for (int gc = 0; gc < 8; gc++) a += base[gc * 1664 + 128 + r];
    buf[nc * 8 + r / 96][r % 96] = a * (1.f / G);
  }
  __syncthreads();
  if (t < 128) {                           // sm011[n]
    float s = 0.f;
    for (int e = 0; e < E; e++) s += buf[t][e];
    sm011[t] = s * (1.f / E);
  }
  if (t < 96) {                            // sce1[e]
    const float* wc1 = Wcrit + (1 * CO + o) * N;
    float c = 0.f;
    for (int n = 0; n < N; n++) c += wc1[n] * buf[n][t];
    sce1[t] = c;
  }
  __syncthreads();
  // fold s001b partials into buf
#pragma unroll
  for (int k = 0; k < 48; k++) {
    int i = t + k * 256;
    int nc = i / 768, r = i % 768;
    const float* base = pbB + (size_t)(nc * 8) * 1664;
    float m = -INFINITY;
#pragma unroll
    for (int gc = 0; gc < 8; gc++) m = fmaxf(m, base[gc * 1664 + 896 + r]);
    buf[nc * 8 + r / 96][r % 96] = lrelu(m);
  }
  __syncthreads();
  if (t < 128) {                           // sm001[n]
    float s = 0.f;
    for (int e = 0; e < E; e++) s += buf[t][e];
    sm001[t] = s * (1.f / E);
  }
  if (t < 96) {                            // sce[e]
    const float* wc2 = Wcrit + (2 * CO + o) * N;
    float c = 0.f;
    for (int n = 0; n < N; n++) c += wc2[n] * buf[n][t];
    sce[t] = sce1[t] + c + bcrit[CO + o] + bcrit[2 * CO + o];
  }
  __syncthreads();
  if (t < P) {                             // actions + scp
    const float* wa0 = Wact + o * N;
    const float* wa1 = Wact + (1 * CO + o) * N;
    const float* wa2 = Wact + (2 * CO + o) * N;
    const float* wc0 = Wcrit + o * N;
    float a = 0.f, c = 0.f, aa = 0.f;
    for (int n = 0; n < N; n++) {
      float m = m110s[n][t];
      a += wa0[n] * m;
      c += wc0[n] * m;
      aa += wa1[n] * sm011[n] + wa2[n] * sm001[n];
    }
    float act = a + aa + bact[o] + bact[CO + o] + bact[2 * CO + o];
    out[(b * CO + o) * P + t] = lrelu(act);
    scp[t] = c + bcrit[o];
  }
  __syncthreads();
  if (t < P) {
    float m = -INFINITY;
    for (int e = 0; e < E; e++) m = fmaxf(m, lrelu(scp[t] + sce[e]));
    srow[t] = m;
  } else if (t < P + E) {
    int e = t - P;
    float m = -INFINITY;
    for (int p = 0; p < P; p++) m = fmaxf(m, lrelu(scp[p] + sce[e]));
    scol[e] = m;
  }
  __syncthreads();
  if (t == 0) {
    float v110 = 0.f, v011 = 0.f;
    for (int p = 0; p < P; p++) v110 += srow[p];
    for (int e = 0; e < E; e++) v011 += scol[e];
    out[B * CO * P + b * CO + o] = 2.f + v110 + 2.f * v011;
  }
}

extern "C" void kernel_launch(void* const* d_in, const int* in_sizes, int n_in,
                              void* d_out, int out_size, void* d_ws, size_t ws_size,
                              hipStream_t stream) {
  const float* x110   = (const float*)d_in[0];
  const float* x011   = (const float*)d_in[1];
  const float* x001   = (const float*)d_in[2];
  const float* W0_110 = (const float*)d_in[3];
  const float* b0_110 = (const float*)d_in[4];
  const float* W0_011 = (const float*)d_in[5];
  const float* b0_011 = (const float*)d_in[6];
  const float* W0_001 = (const float*)d_in[7];
  const float* b0_001 = (const float*)d_in[8];
  const float* W1     = (const float*)d_in[9];
  const float* b1     = (const float*)d_in[10];
  const float* Wact   = (const float*)d_in[11];
  const float* bact   = (const float*)d_in[12];
  const float* Wcrit  = (const float*)d_in[13];
  const float* bcrit  = (const float*)d_in[14];
  float* out = (float*)d_out;
  float* w = (float*)d_ws;

  float* U1     = w + OFF_U1;
  float* V1     = w + OFF_V1;
  float* maxpU0 = w + OFF_MAXPU0;
  float* maxeV0 = w + OFF_MAXEV0;
  float* mp110  = w + OFF_MP110;
  float* mg110  = w + OFF_MG110;
  float* s001a  = w + OFF_S001A;
  float* rmpG   = w + OFF_RMP;
  float* rmgG   = w + OFF_RMG;
  float* rmeG   = w + OFF_RME;
  float* rmg011 = w + OFF_RMG011;
  float* wT     = w + OFF_WT;
  float* partB  = w + OFF_PART;

  k_layer0<<<256, 256, 0, stream>>>(x110, x011, x001, W0_110, b0_110, W0_011,
                                    b0_011, W0_001, b0_001, W1,
                                    maxpU0, maxeV0, mp110, mg110, s001a,
                                    rmpG, rmgG, rmeG, rmg011, wT);
  k_layer1c<<<256, 512, 0, stream>>>(x110, x011, x001, W0_110, b0_110, W0_011,
                                     b0_011, W0_001, b0_001,
                                     maxpU0, maxeV0, rmpG, rmgG, rmeG, rmg011,
                                     wT, U1, V1);
  k_post3<<<256, 256, 0, stream>>>(U1, V1, s001a, mp110, mg110, wT, b1, partB);
  k_final<<<4, 256, 0, stream>>>(partB, Wact, bact, Wcrit, bcrit, out);
}